// Round 4
// baseline (223.381 us; speedup 1.0000x reference)
//
#include <hip/hip_runtime.h>
#include <math.h>

#define SS 8192
#define HH 2048
#define NBLK 256
#define NTHR 512

// Persistent module state. g_v2 is zero at module load and re-zeroed by
// block 0 at the end of every launch, so each launch starts clean.
// Barrier state is sense-reversal: count returns to 0, gen grows forever.
__device__ unsigned g_count = 0;
__device__ unsigned g_gen   = 0;
__device__ __align__(16) float g_v2[HH];

// Device-scope grid barrier. Safe: 256 blocks, __launch_bounds__(512,2)
// guarantees >=1 block/CU on 256 CUs -> all blocks co-resident.
// __syncthreads() drains vmcnt (compiler emits s_waitcnt vmcnt(0) before
// s_barrier), so all the block's atomics/stores are complete before arrival.
__device__ __forceinline__ void grid_barrier() {
    __syncthreads();
    if (threadIdx.x == 0) {
        __threadfence();   // release: write-back L2 (agent scope)
        unsigned my  = __hip_atomic_load(&g_gen, __ATOMIC_RELAXED,
                                         __HIP_MEMORY_SCOPE_AGENT);
        unsigned old = __hip_atomic_fetch_add(&g_count, 1u, __ATOMIC_ACQ_REL,
                                              __HIP_MEMORY_SCOPE_AGENT);
        if (old == NBLK - 1u) {
            __hip_atomic_store(&g_count, 0u, __ATOMIC_RELAXED,
                               __HIP_MEMORY_SCOPE_AGENT);
            __hip_atomic_fetch_add(&g_gen, 1u, __ATOMIC_RELEASE,
                                   __HIP_MEMORY_SCOPE_AGENT);
        } else {
            while (__hip_atomic_load(&g_gen, __ATOMIC_ACQUIRE,
                                     __HIP_MEMORY_SCOPE_AGENT) == my)
                __builtin_amdgcn_s_sleep(2);
        }
        __threadfence();   // acquire: invalidate caches
    }
    __syncthreads();
}

__global__ __launch_bounds__(NTHR, 2) void fused_kernel(
    const float* __restrict__ enc,
    const float* __restrict__ W,
    const float* __restrict__ w,
    float* __restrict__ out,
    float* __restrict__ sc)
{
    const int b = blockIdx.x;
    const int t = threadIdx.x;

    // ---- Phase 1: g_v2[col] += sum over 8 rows of w[j]*W[j, HH+col] ----
    // Block b: rows 8b..8b+7, all 2048 cols (512 thr x float4). 16 MB total.
    {
        const int row0 = b * 8;
        const float4* base =
            (const float4*)(W + (size_t)row0 * (2 * HH) + HH) + t;
        float4 acc = {0.f, 0.f, 0.f, 0.f};
#pragma unroll
        for (int j = 0; j < 8; ++j) {
            float4 a = base[(size_t)j * ((2 * HH) / 4)];
            float wj = w[row0 + j];              // block-uniform -> s_load
            acc.x += wj * a.x; acc.y += wj * a.y;
            acc.z += wj * a.z; acc.w += wj * a.w;
        }
        float* dst = g_v2 + t * 4;
        atomicAdd(dst + 0, acc.x);
        atomicAdd(dst + 1, acc.y);
        atomicAdd(dst + 2, acc.z);
        atomicAdd(dst + 3, acc.w);
    }

    grid_barrier();

    // ---- Phase 2: sc[row] = enc[row,:] . v2 ----
    // 8 waves/block, v2 fragment in regs, 4 rows/wave -> 32 rows/block.
    {
        const int wave = t >> 6;
        const int lane = t & 63;
        const float4* v = (const float4*)g_v2;
        float4 vf[8];
#pragma unroll
        for (int i = 0; i < 8; ++i) vf[i] = v[lane + i * 64];

        const int row_base = b * 32 + wave * 4;
#pragma unroll
        for (int rr = 0; rr < 4; ++rr) {
            const int row = row_base + rr;
            const float4* e = (const float4*)(enc + (size_t)row * HH);
            float acc = 0.0f;
#pragma unroll
            for (int i = 0; i < 8; ++i) {
                float4 a = e[lane + i * 64];
                acc += a.x * vf[i].x + a.y * vf[i].y
                     + a.z * vf[i].z + a.w * vf[i].w;
            }
#pragma unroll
            for (int off = 32; off > 0; off >>= 1)
                acc += __shfl_down(acc, off);
            if (lane == 0) sc[row] = acc;
        }
    }

    grid_barrier();

    // ---- Phase 3: softmax. Every block redundantly reduces all 8192
    // scores (32 KB, L2-resident) and writes its own 32-element slice. ----
    {
        __shared__ float red[8];
        const int lane = t & 63;
        const int wid  = t >> 6;

        float vals[16];
        float m = -INFINITY;
#pragma unroll
        for (int i = 0; i < 16; ++i) {
            vals[i] = sc[t + i * 512];
            m = fmaxf(m, vals[i]);
        }
#pragma unroll
        for (int off = 1; off < 64; off <<= 1)
            m = fmaxf(m, __shfl_xor(m, off));
        if (lane == 0) red[wid] = m;
        __syncthreads();
#pragma unroll
        for (int k = 0; k < 8; ++k) m = fmaxf(m, red[k]);

        float s = 0.0f;
#pragma unroll
        for (int i = 0; i < 16; ++i)
            s += __expf(vals[i] - m);
#pragma unroll
        for (int off = 1; off < 64; off <<= 1)
            s += __shfl_xor(s, off);
        __syncthreads();              // everyone done reading red (max)
        if (lane == 0) red[wid] = s;
        __syncthreads();
        float ss = 0.0f;
#pragma unroll
        for (int k = 0; k < 8; ++k) ss += red[k];
        const float inv = 1.0f / ss;

        if (t < 32) {
            const int e = b * 32 + t;
            out[e] = __expf(sc[e] - m) * inv;
        }

        // Re-zero g_v2 for the next launch (g_v2 not read after barrier 2).
        if (b == 0)
            ((float4*)g_v2)[t] = make_float4(0.f, 0.f, 0.f, 0.f);
    }
}

extern "C" void kernel_launch(void* const* d_in, const int* in_sizes, int n_in,
                              void* d_out, int out_size, void* d_ws, size_t ws_size,
                              hipStream_t stream) {
    const float* enc   = (const float*)d_in[0];  // (S,1,H) -> (S,H)
    // d_in[1] = hidden : constant score shift -> cancels in softmax
    const float* W_att = (const float*)d_in[2];  // (H, 2H)
    // d_in[3] = b_att  : constant shift -> cancels
    const float* w     = (const float*)d_in[4];  // (1, H)

    float* out = (float*)d_out;                  // 8192 floats (1,1,S)
    float* sc  = (float*)d_ws;                   // 8192 floats (raw scores)

    hipLaunchKernelGGL(fused_kernel, dim3(NBLK), dim3(NTHR), 0, stream,
                       enc, W_att, w, out, sc);
}

// Round 5
// 132.076 us; speedup vs baseline: 1.6913x; 1.6913x over previous
//
#include <hip/hip_runtime.h>
#include <math.h>

#define SS 8192
#define HH 2048
#define NBLK 256
#define NTHR 512
#define CSB 64                 // blocks doing colsum work in phase 1
#define CSROWS (HH / CSB)      // 32 rows per colsum block

// Persistent module state. g_v2 zero at module load, re-zeroed (via coherent
// atomic stores) at the end of every launch. g_ctr is a monotone barrier
// counter (sense embedded in the running count) - single address, so all
// barrier ops serialize at one coherent-point bank; no cross-address races.
__device__ unsigned g_ctr = 0;
__device__ __align__(16) float g_v2[HH] = {};

// Fence-free grid barrier. Correctness: all cross-block data is exchanged
// exclusively through agent-scope atomics (which execute at the coherent
// point, bypassing the non-coherent per-XCD L2s). __syncthreads() drains
// vmcnt for every wave of the block, so those atomics are RETIRED at the
// coherent point before the leader's fetch_add - any coherent read after
// the barrier must observe them. Hence no __threadfence (no buffer_wbl2 /
// buffer_inv L2-walk storm, which cost ~50 us/barrier in R1/R4).
// Deadlock-safe: 256 blocks <= 256 CUs, all co-resident.
__device__ __forceinline__ void grid_barrier() {
    __syncthreads();
    if (threadIdx.x == 0) {
        unsigned old = __hip_atomic_fetch_add(&g_ctr, 1u, __ATOMIC_RELAXED,
                                              __HIP_MEMORY_SCOPE_AGENT);
        unsigned target = (old / NBLK + 1u) * NBLK;
        while (__hip_atomic_load(&g_ctr, __ATOMIC_RELAXED,
                                 __HIP_MEMORY_SCOPE_AGENT) < target)
            __builtin_amdgcn_s_sleep(16);   // ~1024 cyc/poll, keeps bank cool
    }
    asm volatile("" ::: "memory");          // compiler-only ordering fence
    __syncthreads();
}

__global__ __launch_bounds__(NTHR, 2) void fused_kernel(
    const float* __restrict__ enc,
    const float* __restrict__ W,
    const float* __restrict__ w,
    float* __restrict__ out,
    float* __restrict__ sc)
{
    const int b = blockIdx.x;
    const int t = threadIdx.x;

    // ---- Phase 1 (blocks 0..CSB-1): g_v2[col] += sum_j w[j]*W[j, HH+col].
    // 64 blocks x 32 rows, 512 thr x float4 = all 2048 cols. 16 MB stream,
    // 128K atomicAdds (64 per address) into the coherent point.
    if (b < CSB) {
        const int row0 = b * CSROWS;
        const float4* base =
            (const float4*)(W + (size_t)row0 * (2 * HH) + HH) + t;
        float4 acc = {0.f, 0.f, 0.f, 0.f};
#pragma unroll 8
        for (int j = 0; j < CSROWS; ++j) {
            float4 a = base[(size_t)j * ((2 * HH) / 4)];
            float wj = w[row0 + j];              // block-uniform -> s_load
            acc.x += wj * a.x; acc.y += wj * a.y;
            acc.z += wj * a.z; acc.w += wj * a.w;
        }
        float* dst = g_v2 + t * 4;
        atomicAdd(dst + 0, acc.x);
        atomicAdd(dst + 1, acc.y);
        atomicAdd(dst + 2, acc.z);
        atomicAdd(dst + 3, acc.w);
    }

    grid_barrier();

    // ---- Phase 2: sc[row] = enc[row,:] . v2 ----
    // Coherent-copy g_v2 into LDS once per block, then 8 waves x 4 rows.
    __shared__ float v2s[HH];
#pragma unroll
    for (int k = 0; k < 4; ++k)
        v2s[t + k * 512] = __hip_atomic_load(&g_v2[t + k * 512],
                                             __ATOMIC_RELAXED,
                                             __HIP_MEMORY_SCOPE_AGENT);
    __syncthreads();
    {
        const int wave = t >> 6;
        const int lane = t & 63;
        const float4* v4 = (const float4*)v2s;
        float4 vf[8];
#pragma unroll
        for (int i = 0; i < 8; ++i) vf[i] = v4[lane + i * 64];

        const int row_base = b * 32 + wave * 4;
#pragma unroll
        for (int rr = 0; rr < 4; ++rr) {
            const int row = row_base + rr;
            const float4* e = (const float4*)(enc + (size_t)row * HH);
            float acc = 0.0f;
#pragma unroll
            for (int i = 0; i < 8; ++i) {
                float4 a = e[lane + i * 64];
                acc += a.x * vf[i].x + a.y * vf[i].y
                     + a.z * vf[i].z + a.w * vf[i].w;
            }
#pragma unroll
            for (int off = 32; off > 0; off >>= 1)
                acc += __shfl_down(acc, off);
            if (lane == 0)
                __hip_atomic_store(&sc[row], acc, __ATOMIC_RELAXED,
                                   __HIP_MEMORY_SCOPE_AGENT);
        }
    }

    grid_barrier();

    // ---- Phase 3: softmax. Every block redundantly reduces all 8192
    // scores via coherent loads (ws L2 lines may hold stale poison) and
    // writes its own 32-element slice with plain stores. ----
    {
        __shared__ float red[8];
        const int lane = t & 63;
        const int wid  = t >> 6;

        float vals[16];
        float m = -INFINITY;
#pragma unroll
        for (int i = 0; i < 16; ++i) {
            vals[i] = __hip_atomic_load(&sc[t + i * 512], __ATOMIC_RELAXED,
                                        __HIP_MEMORY_SCOPE_AGENT);
            m = fmaxf(m, vals[i]);
        }
#pragma unroll
        for (int off = 1; off < 64; off <<= 1)
            m = fmaxf(m, __shfl_xor(m, off));
        if (lane == 0) red[wid] = m;
        __syncthreads();
#pragma unroll
        for (int k = 0; k < 8; ++k) m = fmaxf(m, red[k]);

        float s = 0.0f;
#pragma unroll
        for (int i = 0; i < 16; ++i)
            s += __expf(vals[i] - m);
#pragma unroll
        for (int off = 1; off < 64; off <<= 1)
            s += __shfl_xor(s, off);
        __syncthreads();              // everyone done reading red (max)
        if (lane == 0) red[wid] = s;
        __syncthreads();
        float ss = 0.0f;
#pragma unroll
        for (int k = 0; k < 8; ++k) ss += red[k];
        const float inv = 1.0f / ss;

        if (t < 32) {
            const int e = b * 32 + t;
            float sv = __hip_atomic_load(&sc[e], __ATOMIC_RELAXED,
                                         __HIP_MEMORY_SCOPE_AGENT);
            out[e] = __expf(sv - m) * inv;
        }

        // Re-zero g_v2 for the next launch (unread after barrier 2).
        // Atomic stores -> land at the coherent point, no flush needed.
        if (b == NBLK - 1) {
#pragma unroll
            for (int k = 0; k < 4; ++k)
                __hip_atomic_store(&g_v2[t + k * 512], 0.0f,
                                   __ATOMIC_RELAXED,
                                   __HIP_MEMORY_SCOPE_AGENT);
        }
    }
}

extern "C" void kernel_launch(void* const* d_in, const int* in_sizes, int n_in,
                              void* d_out, int out_size, void* d_ws, size_t ws_size,
                              hipStream_t stream) {
    const float* enc   = (const float*)d_in[0];  // (S,1,H) -> (S,H)
    // d_in[1] = hidden : constant score shift -> cancels in softmax
    const float* W_att = (const float*)d_in[2];  // (H, 2H)
    // d_in[3] = b_att  : constant shift -> cancels
    const float* w     = (const float*)d_in[4];  // (1, H)

    float* out = (float*)d_out;                  // 8192 floats (1,1,S)
    float* sc  = (float*)d_ws;                   // 8192 floats (raw scores)

    hipLaunchKernelGGL(fused_kernel, dim3(NBLK), dim3(NTHR), 0, stream,
                       enc, W_att, w, out, sc);
}